// Round 4
// baseline (192.595 us; speedup 1.0000x reference)
//
#include <hip/hip_runtime.h>
#include <hip/hip_bf16.h>

// Chamfer distance, B=4, N=M=8192, D=3, fp32.
// d2(p,t) = |p|^2 + (|t|^2 - 2 p.t).
// DB chunk staged in LDS pair-transposed rows of 8 floats
// [x0 x1 y0 y1 z0 z1 w0 w1] (x=-2*t.x etc., w=|t|^2), read back as two
// ds_read_b128 broadcasts. Two DB points per step cost 3 v_pk_fma_f32 +
// 1 v_min3_f32 per query = 2 VALU/pair. Q=8 queries register-blocked with
// explicit scalars. Round-3 lesson: at 2 blocks/CU the ~120cyc ds_read
// latency was exposed (VALUBusy 25%) -> S=32 gives 1024 blocks = 4/CU =
// 4 waves/SIMD, enough TLP to cover it (4x80cyc work > 200cyc load+use).
// Partial mins combined via uint-bitpattern atomicMin (d2>=0); last
// arriving block reduces and writes out = sum/32768 + lamda*bpp.

typedef float v2f __attribute__((ext_vector_type(2)));

#define T 256      // threads per block
#define Q 8        // query points per thread
#define S 32       // db splits
#define CH 256     // db chunk size (8192 / S)
#define NPTS 8192
#define NCOMBO 8   // 2 directions x 4 batches
#define NB (NCOMBO * 4 * S)   // 1024 blocks
#define CINIT 0x7F7F7F7Fu     // counter initial value (memset 0x7F)

#define FOR8(OP) OP(0) OP(1) OP(2) OP(3) OP(4) OP(5) OP(6) OP(7)

__global__ __launch_bounds__(T, 4) void chamfer_fused(
    const float* __restrict__ pred, const float* __restrict__ target,
    unsigned int* __restrict__ partmin, unsigned int* __restrict__ counter,
    const float* __restrict__ bpp, const float* __restrict__ lamda,
    float* __restrict__ out)
{
    __shared__ float4 s4[(CH / 2 + 1) * 2];   // rows of 2 float4; +1 row pad

    const int bid   = blockIdx.x;
    const int dbc   = bid & (S - 1);
    const int qc    = (bid >> 5) & 3;
    const int combo = bid >> 7;          // 0..7
    const int dir   = combo & 1;
    const int b     = combo >> 1;

    const float* qptr = (dir == 0 ? pred : target) + (size_t)b * NPTS * 3;
    const float* dptr = (dir == 0 ? target : pred) + (size_t)b * NPTS * 3;
    const int tid = threadIdx.x;

    // --- stage db chunk into LDS, transformed + pair-transposed ---
    for (int p = tid; p < CH; p += T) {
        int gj = dbc * CH + p;
        float x = dptr[gj * 3 + 0];
        float y = dptr[gj * 3 + 1];
        float z = dptr[gj * 3 + 2];
        float* f = (float*)s4 + (p >> 1) * 8 + (p & 1);
        f[0] = -2.f * x;
        f[2] = -2.f * y;
        f[4] = -2.f * z;
        f[6] = fmaf(x, x, fmaf(y, y, z * z));
    }

    // --- load Q query points into explicit scalar registers ---
    const int qbase = qc * (T * Q) + tid;
#define LOADQ(k) \
    const int   qi##k  = qbase + (k) * T; \
    const float qxs##k = qptr[qi##k * 3 + 0]; \
    const float qys##k = qptr[qi##k * 3 + 1]; \
    const float qzs##k = qptr[qi##k * 3 + 2]; \
    const v2f   qx##k  = {qxs##k, qxs##k}; \
    const v2f   qy##k  = {qys##k, qys##k}; \
    const v2f   qz##k  = {qzs##k, qzs##k}; \
    float m##k = 3.4e38f;
    FOR8(LOADQ)
#undef LOADQ

    __syncthreads();

    // --- main loop: 2 db points/iter, 1-deep prefetch ---
    float4 A = s4[0], Bv = s4[1];
    for (int j = 0; j < CH / 2; ++j) {
        float4 nA = s4[2 * j + 2];
        float4 nB = s4[2 * j + 3];
        v2f xx = {A.x, A.y}, yy = {A.z, A.w};
        v2f zz = {Bv.x, Bv.y}, ww = {Bv.z, Bv.w};
#define BODY(k) { \
        v2f s = __builtin_elementwise_fma(zz, qz##k, ww); \
        s = __builtin_elementwise_fma(yy, qy##k, s); \
        s = __builtin_elementwise_fma(xx, qx##k, s); \
        m##k = fminf(fminf(m##k, s.x), s.y); }
        FOR8(BODY)
#undef BODY
        A = nA; Bv = nB;
    }

    // --- epilogue: add |q|^2, clamp >= 0, atomicMin on bit pattern ---
#define EPI(k) { \
    float qq = fmaf(qxs##k, qxs##k, fmaf(qys##k, qys##k, qzs##k * qzs##k)); \
    float d2 = fmaxf(m##k + qq, 0.0f); \
    atomicMin(&partmin[combo * NPTS + qi##k], __float_as_uint(d2)); }
    FOR8(EPI)
#undef EPI

    // --- last-arriving block reduces everything ---
    __threadfence();   // release our atomicMins before counter bump
    __shared__ int lastFlag;
    if (tid == 0)
        lastFlag = (atomicAdd(counter, 1u) == CINIT + (unsigned)(NB - 1));
    __syncthreads();
    if (lastFlag) {
        float s = 0.f;
        for (int i = tid; i < NCOMBO * NPTS; i += T)
            s += __uint_as_float(__hip_atomic_load(
                    &partmin[i], __ATOMIC_RELAXED, __HIP_MEMORY_SCOPE_AGENT));
#pragma unroll
        for (int off = 32; off; off >>= 1)
            s += __shfl_down(s, off, 64);
        __shared__ float red[4];
        int lane = tid & 63, wid = tid >> 6;
        if (lane == 0) red[wid] = s;
        __syncthreads();
        if (tid == 0)
            out[0] = (red[0] + red[1] + red[2] + red[3]) * (1.f / 32768.f)
                     + lamda[0] * bpp[0];
    }
}

extern "C" void kernel_launch(void* const* d_in, const int* in_sizes, int n_in,
                              void* d_out, int out_size, void* d_ws, size_t ws_size,
                              hipStream_t stream) {
    const float* pred   = (const float*)d_in[0];
    const float* target = (const float*)d_in[1];
    const float* bpp    = (const float*)d_in[2];
    const float* lamda  = (const float*)d_in[3];
    unsigned int* partmin = (unsigned int*)d_ws;
    unsigned int* counter = partmin + NCOMBO * NPTS;

    // One memset covers partmin (-> 3.39e38 bitpattern) AND counter (-> CINIT)
    (void)hipMemsetAsync(partmin, 0x7F,
                         ((size_t)NCOMBO * NPTS + 1) * sizeof(unsigned), stream);

    chamfer_fused<<<NB, T, 0, stream>>>(pred, target, partmin, counter,
                                        bpp, lamda, (float*)d_out);
}

// Round 5
// 140.785 us; speedup vs baseline: 1.3680x; 1.3680x over previous
//
#include <hip/hip_runtime.h>
#include <hip/hip_bf16.h>

// Chamfer distance, B=4, N=M=8192, D=3, fp32.
// d2(p,t) = |p|^2 + (|t|^2 - 2 p.t), |p|^2 added in epilogue.
//
// Round-4 lesson: the main loop is NOT the bottleneck (VALU ~17us/SIMD); the
// 110us stall = 2M contended device atomics + serial agent-scope-load tail
// (time-avg occupancy 5.7 waves/CU). Round-5 restructure:
//  * prep kernel (replaces memset dispatch): writes pair-transposed
//    transformed DB rows [x0 x1 y0 y1 z0 z1 w0 w1] (x=-2*t.x, w=|t|^2) into
//    ws, inits partmin=+3.39e38 and counter=0.
//  * main kernel: DB rows are WAVE-UNIFORM -> uniform float4 loads scalarize
//    to s_load (SGPR-resident, no LDS, no ds_read latency, no syncthreads in
//    loop). v_pk_fma_f32 takes the 64-bit SGPR pair directly: 3 pk_fma +
//    2 min per query per 2 DB points, Q=8 queries register-blocked.
//  * S=16 (1M atomicMins, round-1-proven hideable), 512 blocks.
//  * tail: release adds on counter; last block acquires, then PLAIN coalesced
//    float4 loads (not agent-scope scalar), reduces, writes out.

typedef float v2f __attribute__((ext_vector_type(2)));

#define T 256      // threads per block
#define Q 8        // query points per thread
#define S 16       // db splits
#define CH (8192 / S)          // 512 db points per block
#define NPTS 8192
#define NCOMBO 8               // 2 directions x 4 batches
#define QSL (NPTS / (T * Q))   // 4 query slices
#define NB (NCOMBO * QSL * S)  // 512 blocks

#define FOR8(OP) OP(0) OP(1) OP(2) OP(3) OP(4) OP(5) OP(6) OP(7)

__global__ __launch_bounds__(256) void prep(
    const float* __restrict__ pred, const float* __restrict__ target,
    float* __restrict__ dbT, unsigned* __restrict__ partmin,
    unsigned* __restrict__ counter)
{
    int i = blockIdx.x * 256 + threadIdx.x;   // 0 .. 65535
    int combo = i >> 13;
    int p = i & (NPTS - 1);
    int dir = combo & 1, b = combo >> 1;
    // combo's DB side: dir==0 queries pred -> db is target; dir==1 -> db is pred
    const float* dptr = (dir == 0 ? target : pred) + (size_t)b * NPTS * 3;
    float x = dptr[p * 3 + 0], y = dptr[p * 3 + 1], z = dptr[p * 3 + 2];
    float* row = dbT + (size_t)combo * NPTS * 4 + (size_t)(p >> 1) * 8 + (p & 1);
    row[0] = -2.f * x;
    row[2] = -2.f * y;
    row[4] = -2.f * z;
    row[6] = fmaf(x, x, fmaf(y, y, z * z));
    partmin[i] = 0x7F7F7F7Fu;                 // +3.39e38 bit pattern
    if (i == 0) *counter = 0u;
}

__global__ __launch_bounds__(T, 2) void chamfer_main(
    const float* __restrict__ pred, const float* __restrict__ target,
    const float4* __restrict__ dbT4, unsigned* __restrict__ partmin,
    unsigned* __restrict__ counter,
    const float* __restrict__ bpp, const float* __restrict__ lamda,
    float* __restrict__ out)
{
    const int bid   = blockIdx.x;
    const int dbc   = bid & (S - 1);          // 4 bits
    const int qc    = (bid >> 4) & (QSL - 1); // 2 bits
    const int combo = bid >> 6;               // 3 bits, 0..7
    const int dir   = combo & 1;
    const int b     = combo >> 1;

    const float* qptr = (dir == 0 ? pred : target) + (size_t)b * NPTS * 3;
    const int tid = threadIdx.x;

    // block's DB rows: float4 index = combo*NPTS + dbc*CH (2 float4 per row)
    const float4* __restrict__ dbp = dbT4 + (size_t)combo * NPTS + (size_t)dbc * CH;

    // --- load Q query points into explicit scalar registers ---
    const int qbase = qc * (T * Q) + tid;
#define LOADQ(k) \
    const int   qi##k  = qbase + (k) * T; \
    const float qxs##k = qptr[qi##k * 3 + 0]; \
    const float qys##k = qptr[qi##k * 3 + 1]; \
    const float qzs##k = qptr[qi##k * 3 + 2]; \
    const v2f   qx##k  = {qxs##k, qxs##k}; \
    const v2f   qy##k  = {qys##k, qys##k}; \
    const v2f   qz##k  = {qzs##k, qzs##k}; \
    float m##k = 3.4e38f;
    FOR8(LOADQ)
#undef LOADQ

    // --- main loop: 2 db points / iter, wave-uniform s_load rows ---
#pragma unroll 4
    for (int j = 0; j < CH / 2; ++j) {
        float4 a = dbp[2 * j];         // [x0 x1 y0 y1]
        float4 c = dbp[2 * j + 1];     // [z0 z1 w0 w1]
        v2f xx = {a.x, a.y}, yy = {a.z, a.w};
        v2f zz = {c.x, c.y}, ww = {c.z, c.w};
#define BODY(k) { \
        v2f s = __builtin_elementwise_fma(zz, qz##k, ww); \
        s = __builtin_elementwise_fma(yy, qy##k, s); \
        s = __builtin_elementwise_fma(xx, qx##k, s); \
        m##k = fminf(fminf(m##k, s.x), s.y); }
        FOR8(BODY)
#undef BODY
    }

    // --- epilogue: add |q|^2, clamp >= 0, atomicMin on bit pattern ---
#define EPI(k) { \
    float qq = fmaf(qxs##k, qxs##k, fmaf(qys##k, qys##k, qzs##k * qzs##k)); \
    float d2 = fmaxf(m##k + qq, 0.0f); \
    atomicMin(&partmin[combo * NPTS + qi##k], __float_as_uint(d2)); }
    FOR8(EPI)
#undef EPI

    // --- completion protocol ---
    __threadfence();      // drain our atomicMins to the coherence point
    __syncthreads();      // all threads of block done above
    __shared__ int lastFlag;
    if (tid == 0) {
        unsigned prev = __hip_atomic_fetch_add(counter, 1u, __ATOMIC_ACQ_REL,
                                               __HIP_MEMORY_SCOPE_AGENT);
        lastFlag = (prev == (unsigned)(NB - 1));
    }
    __syncthreads();

    // --- last-arriving block: acquire, then plain coalesced reduce ---
    if (lastFlag) {
        (void)__hip_atomic_load(counter, __ATOMIC_ACQUIRE,
                                __HIP_MEMORY_SCOPE_AGENT);
        const float4* pm4 = (const float4*)partmin;
        float ssum = 0.f;
#pragma unroll
        for (int it = 0; it < (NCOMBO * NPTS / 4) / T; ++it) {   // 64 iters
            float4 v = pm4[(size_t)it * T + tid];
            ssum += (v.x + v.y) + (v.z + v.w);
        }
#pragma unroll
        for (int off = 32; off; off >>= 1)
            ssum += __shfl_down(ssum, off, 64);
        __shared__ float red[4];
        int lane = tid & 63, wid = tid >> 6;
        if (lane == 0) red[wid] = ssum;
        __syncthreads();
        if (tid == 0)
            out[0] = (red[0] + red[1] + red[2] + red[3]) * (1.f / 32768.f)
                     + lamda[0] * bpp[0];
    }
}

extern "C" void kernel_launch(void* const* d_in, const int* in_sizes, int n_in,
                              void* d_out, int out_size, void* d_ws, size_t ws_size,
                              hipStream_t stream) {
    const float* pred   = (const float*)d_in[0];
    const float* target = (const float*)d_in[1];
    const float* bpp    = (const float*)d_in[2];
    const float* lamda  = (const float*)d_in[3];

    float*    dbT     = (float*)d_ws;                         // 1 MB
    unsigned* partmin = (unsigned*)(dbT + (size_t)NCOMBO * NPTS * 4); // 256 KB
    unsigned* counter = partmin + NCOMBO * NPTS;

    prep<<<(NCOMBO * NPTS) / 256, 256, 0, stream>>>(pred, target, dbT,
                                                    partmin, counter);
    chamfer_main<<<NB, T, 0, stream>>>(pred, target, (const float4*)dbT,
                                       partmin, counter, bpp, lamda,
                                       (float*)d_out);
}